// Round 5
// baseline (288.664 us; speedup 1.0000x reference)
//
#include <hip/hip_runtime.h>
#include <math.h>

#define NROWS 32768
#define DIM   256
#define KCODES 1024
#define RPB   32      // rows per block
#define CANDC 12      // candidate cap per row

// ---- ws layout (bytes) ----
//      0 : double loss accumulator
//     16 : se[1024]   f32  (np-exact codebook row sum-of-squares)
//   4112 : sacb[1024] f32  (codebook abs-sum scratch, unused)
// 270352 : cb_bf16[1024*256] ushort (RTNE bf16 codebook, B-FRAGMENT order)
#define WS_SE    16
#define WS_SACB  4112
#define WS_CBBF  270352

typedef __attribute__((ext_vector_type(8))) short  short8;
typedef __attribute__((ext_vector_type(4))) float  f32x4;

__device__ __forceinline__ unsigned short bf16rtne(float f){
    unsigned int u = __float_as_uint(f);
    return (unsigned short)((u + 0x7FFFu + ((u >> 16) & 1u)) >> 16);
}

__device__ __forceinline__ void gload_lds16(const void* g, void* l){
    __builtin_amdgcn_global_load_lds(
        (const __attribute__((address_space(1))) void*)g,
        (__attribute__((address_space(3))) void*)l, 16, 0, 0);
}

__global__ void init_ws(double* acc) {
    if (threadIdx.x == 0 && blockIdx.x == 0) *acc = 0.0;
}

// Bit-exact numpy pairwise_sum replication for sum(x^2) per row, plus an
// order-free sum(|x|). Used for the codebook (se); x row sums are fused
// into vq_score with the identical instruction sequence.
__global__ void rowsq_kernel(const float* __restrict__ src,
                             float* __restrict__ dst,
                             float* __restrict__ dst_abs, int nrows) {
    const int gtid = blockIdx.x * blockDim.x + threadIdx.x;
    const int wave = gtid >> 6;
    const int lane = threadIdx.x & 63;
    const int rowsub = lane >> 4;
    const int agent  = lane & 15;
    const int half   = agent >> 3;
    const int j      = agent & 7;
    const int row = wave * 4 + rowsub;
    if (row >= nrows) return;

    const float* p = src + (size_t)row * DIM + half * 128 + j;
    float x0 = p[0];
    float r  = __fmul_rn(x0, x0);
    float ra = fabsf(x0);
    #pragma unroll
    for (int i = 1; i < 16; ++i) {
        float xi = p[8 * i];
        r  = __fadd_rn(r, __fmul_rn(xi, xi));
        ra += fabsf(xi);
    }
    r = __fadd_rn(r, __shfl_xor(r, 1, 64));  ra += __shfl_xor(ra, 1, 64);
    r = __fadd_rn(r, __shfl_xor(r, 2, 64));  ra += __shfl_xor(ra, 2, 64);
    r = __fadd_rn(r, __shfl_xor(r, 4, 64));  ra += __shfl_xor(ra, 4, 64);
    r = __fadd_rn(r, __shfl_xor(r, 8, 64));  ra += __shfl_xor(ra, 8, 64);
    if (agent == 0) { dst[row] = r; dst_abs[row] = ra; }
}

// Codebook -> bf16 in MFMA B-fragment order:
//   dst[((T*8+s)*64 + lane)*8 + e] = bf16(cb[(T*16 + (lane&15))*256 + s*32 + (lane>>4)*8 + e])
__global__ void cvt_cb_kernel(const float* __restrict__ cb,
                              unsigned short* __restrict__ dst) {
    int o = blockIdx.x * 256 + threadIdx.x;   // 0..32767 short8 units
    int lane = o & 63;
    int ts   = o >> 6;                        // T*8 + s
    int code = (ts >> 3) * 16 + (lane & 15);
    int k0   = (ts & 7) * 32 + (lane >> 4) * 8;
    const float4* p = (const float4*)(cb + (size_t)code * DIM + k0);
    float4 a = p[0], b = p[1];
    short8 f;
    f[0] = (short)bf16rtne(a.x); f[1] = (short)bf16rtne(a.y);
    f[2] = (short)bf16rtne(a.z); f[3] = (short)bf16rtne(a.w);
    f[4] = (short)bf16rtne(b.x); f[5] = (short)bf16rtne(b.y);
    f[6] = (short)bf16rtne(b.z); f[7] = (short)bf16rtne(b.w);
    *(short8*)(dst + (size_t)o * 8) = f;
}

#define FMA4(A, X, E) do {                                       \
    A.x = fmaf(X.x, E.x, A.x); A.y = fmaf(X.y, E.y, A.y);        \
    A.z = fmaf(X.z, E.z, A.z); A.w = fmaf(X.w, E.w, A.w);        \
} while (0)

// 1024 blocks x 4 waves, 32 rows/block, 3 blocks/CU. Wave-private LDS
// triple-buffered B-streaming (4KB chunks, lookahead-2, counted vmcnt, no
// barriers in the main loop). Pass A tracks global min + per-(tile,rowtile)
// mins; qualification is per-rowtile (conservative-correct). Pass B revisits
// only qualifying tiles; pass C rescores candidates with the exact fp32 chain.
__launch_bounds__(256, 3)
__global__ void vq_score(const float* __restrict__ x,
                         const float* __restrict__ cb,
                         const float* __restrict__ se_arr,
                         const unsigned short* __restrict__ cbbf,
                         float* __restrict__ out_q,
                         float* __restrict__ out_idx,
                         double* __restrict__ loss_acc)
{
    // wave-private ring buffers: [wave][ring 0..2][k-substep][lane] = short8
    __shared__ short8 bufs[4][3][4][64];     // 49152 B
    __shared__ float minw[4][RPB];
    __shared__ float thr[RPB];
    __shared__ float sxl[RPB];
    __shared__ float sal[RPB];
    __shared__ unsigned int cnt[RPB];
    __shared__ unsigned int cand[RPB][CANDC];
    __shared__ unsigned long long win[RPB];
    __shared__ unsigned int wcode[RPB];
    __shared__ double lsum[4];

    const int tid  = threadIdx.x;
    const int w    = tid >> 6;
    const int lane = tid & 63;
    const int cc   = lane & 15;
    const int g    = lane >> 4;
    const int n0   = blockIdx.x * RPB;

    if (tid < RPB) { cnt[tid] = 0u; win[tid] = ~0ull; }

    // ---- A fragments: rows rt*16+cc, k = 32s + 8g + e (verified mapping) ----
    short8 afrag[2][8];
    #pragma unroll
    for (int rt = 0; rt < 2; ++rt) {
        const float4* rp = (const float4*)x + (size_t)(n0 + rt * 16 + cc) * 64;
        #pragma unroll
        for (int s = 0; s < 8; ++s) {
            float4 a = rp[s * 8 + g * 2];
            float4 b = rp[s * 8 + g * 2 + 1];
            short8 f;
            f[0] = (short)bf16rtne(a.x); f[1] = (short)bf16rtne(a.y);
            f[2] = (short)bf16rtne(a.z); f[3] = (short)bf16rtne(a.w);
            f[4] = (short)bf16rtne(b.x); f[5] = (short)bf16rtne(b.y);
            f[6] = (short)bf16rtne(b.z); f[7] = (short)bf16rtne(b.w);
            afrag[rt][s] = f;
        }
    }

    // ---- fused np-exact row sums (identical instruction sequence) ----
    {
        const int rowsub = lane >> 4;
        const int agent  = lane & 15;
        const int half   = agent >> 3;
        const int j      = agent & 7;
        #pragma unroll
        for (int q = 0; q < 2; ++q) {
            const int lrow = w * 8 + q * 4 + rowsub;
            const float* p = x + (size_t)(n0 + lrow) * DIM + half * 128 + j;
            float x0 = p[0];
            float r  = __fmul_rn(x0, x0);
            float ra = fabsf(x0);
            #pragma unroll
            for (int i = 1; i < 16; ++i) {
                float xi = p[8 * i];
                r  = __fadd_rn(r, __fmul_rn(xi, xi));
                ra += fabsf(xi);
            }
            r = __fadd_rn(r, __shfl_xor(r, 1, 64));  ra += __shfl_xor(ra, 1, 64);
            r = __fadd_rn(r, __shfl_xor(r, 2, 64));  ra += __shfl_xor(ra, 2, 64);
            r = __fadd_rn(r, __shfl_xor(r, 4, 64));  ra += __shfl_xor(ra, 4, 64);
            r = __fadd_rn(r, __shfl_xor(r, 8, 64));  ra += __shfl_xor(ra, 8, 64);
            if (agent == 0) { sxl[lrow] = r; sal[lrow] = ra; }
        }
    }

    const int T0 = w << 4;        // wave's first 16-code tile index
    const f32x4 fz = {0.f, 0.f, 0.f, 0.f};

    // se for the wave's 256-code slice: statically-indexed registers
    float se_reg[16];
    #pragma unroll
    for (int t = 0; t < 16; ++t) se_reg[t] = se_arr[(T0 + t) * 16 + cc];

    float minr[2][4];
    #pragma unroll
    for (int rt = 0; rt < 2; ++rt)
        #pragma unroll
        for (int r = 0; r < 4; ++r) minr[rt][r] = INFINITY;
    float tilemin0[16], tilemin1[16];    // per-(tile,rowtile) lane-local mins
    f32x4 a0 = fz, a1 = fz;

// chunk c (0..31): tile t = c>>1, half h = c&1 (k-steps h*4..h*4+3), ring c%3
#define ISSUE_C(c) do {                                                       \
    const char* gsrc_ = (const char*)cbbf +                                   \
        (size_t)(((T0 + ((c) >> 1)) * 8 + ((c) & 1) * 4)) * 1024 + lane * 16; \
    _Pragma("unroll")                                                         \
    for (int i_ = 0; i_ < 4; ++i_)                                            \
        gload_lds16(gsrc_ + i_ * 1024, (void*)&bufs[w][(c) % 3][i_][0]);      \
} while (0)

#define WAITV_(N) asm volatile("s_waitcnt vmcnt(" #N ")" ::: "memory")
#define WAITV(N) WAITV_(N)
#define LGKM0 asm volatile("s_waitcnt lgkmcnt(0)" ::: "memory")

#define MFMA4(c) do {                                                         \
    short8 bv_[4];                                                            \
    _Pragma("unroll")                                                         \
    for (int s_ = 0; s_ < 4; ++s_) bv_[s_] = bufs[w][(c) % 3][s_][lane];      \
    _Pragma("unroll")                                                         \
    for (int s_ = 0; s_ < 4; ++s_) {                                          \
        const int ks_ = ((c) & 1) * 4 + s_;                                   \
        a0 = __builtin_amdgcn_mfma_f32_16x16x32_bf16(afrag[0][ks_], bv_[s_], a0, 0, 0, 0); \
        a1 = __builtin_amdgcn_mfma_f32_16x16x32_bf16(afrag[1][ks_], bv_[s_], a1, 0, 0, 0); \
    }                                                                         \
} while (0)

#define EPI(t) do {                                                           \
    const float sec_ = se_reg[(t)];                                           \
    float tm0_ = INFINITY, tm1_ = INFINITY;                                   \
    _Pragma("unroll")                                                         \
    for (int r_ = 0; r_ < 4; ++r_) {                                          \
        float s0_ = fmaf(-2.f, a0[r_], sec_);                                 \
        float s1_ = fmaf(-2.f, a1[r_], sec_);                                 \
        minr[0][r_] = fminf(minr[0][r_], s0_);                                \
        minr[1][r_] = fminf(minr[1][r_], s1_);                                \
        tm0_ = fminf(tm0_, s0_);                                              \
        tm1_ = fminf(tm1_, s1_);                                              \
    }                                                                         \
    tilemin0[(t)] = tm0_;                                                     \
    tilemin1[(t)] = tm1_;                                                     \
} while (0)

// lgkmcnt(0): ds_reads of the chunk whose ring slot we overwrite must be done.
#define STEP(c, W) do {                                                       \
    LGKM0;                                                                    \
    if ((c) + 2 < 32) ISSUE_C((c) + 2);                                       \
    WAITV(W);                                                                 \
    if (((c) & 1) == 0) { a0 = fz; a1 = fz; }                                 \
    MFMA4(c);                                                                 \
    if (((c) & 1) == 1) EPI((c) >> 1);                                        \
} while (0)

    // ---- PASS A: lookahead-2 counted-vmcnt pipeline, no barriers ----
    WAITV(0);              // drain pre-loop VMEM so counts are exact
    ISSUE_C(0); ISSUE_C(1);
    STEP(0, 8);  STEP(1, 8);  STEP(2, 8);  STEP(3, 8);
    STEP(4, 8);  STEP(5, 8);  STEP(6, 8);  STEP(7, 8);
    STEP(8, 8);  STEP(9, 8);  STEP(10, 8); STEP(11, 8);
    STEP(12, 8); STEP(13, 8); STEP(14, 8); STEP(15, 8);
    STEP(16, 8); STEP(17, 8); STEP(18, 8); STEP(19, 8);
    STEP(20, 8); STEP(21, 8); STEP(22, 8); STEP(23, 8);
    STEP(24, 8); STEP(25, 8); STEP(26, 8); STEP(27, 8);
    STEP(28, 8); STEP(29, 8); STEP(30, 4); STEP(31, 0);

    // reduce min across the 16 cc-lanes (row = rt*16 + 4g + r)
    #pragma unroll
    for (int rt = 0; rt < 2; ++rt) {
        #pragma unroll
        for (int r = 0; r < 4; ++r) {
            float v = minr[rt][r];
            v = fminf(v, __shfl_xor(v, 1, 64));
            v = fminf(v, __shfl_xor(v, 2, 64));
            v = fminf(v, __shfl_xor(v, 4, 64));
            v = fminf(v, __shfl_xor(v, 8, 64));
            if (cc == 0) minw[w][rt * 16 + g * 4 + r] = v;
        }
    }
    __syncthreads();
    if (tid < RPB) {
        float mm = fminf(fminf(minw[0][tid], minw[1][tid]),
                         fminf(minw[2][tid], minw[3][tid]));
        // margin: 2*(bf16 input-quant dot error, <= sa*7.7e-6) + f32 chain ulp slack
        thr[tid] = mm + fmaf(sal[tid], 1.6e-5f, 1.0e-4f);
    }
    __syncthreads();

    // ---- per-rowtile tile qualification + PASS B over qualifying tiles ----
    {
        float th[2][4];
        #pragma unroll
        for (int rt = 0; rt < 2; ++rt)
            #pragma unroll
            for (int r = 0; r < 4; ++r) th[rt][r] = thr[rt * 16 + g * 4 + r];
        const float thmax0 = fmaxf(fmaxf(th[0][0], th[0][1]),
                                   fmaxf(th[0][2], th[0][3]));
        const float thmax1 = fmaxf(fmaxf(th[1][0], th[1][1]),
                                   fmaxf(th[1][2], th[1][3]));

        unsigned int qmask = 0;
        #pragma unroll
        for (int t = 0; t < 16; ++t)
            if (__any((tilemin0[t] <= thmax0) || (tilemin1[t] <= thmax1)))
                qmask |= (1u << t);

        unsigned int m = qmask;   // wave-uniform
        while (m) {
            int t = __ffs(m) - 1;
            m &= m - 1;
            short8 bv[8];
            const char* bp = (const char*)cbbf + (size_t)(T0 + t) * 8192 + lane * 16;
            #pragma unroll
            for (int s_ = 0; s_ < 8; ++s_)
                bv[s_] = *(const short8*)(bp + s_ * 1024);
            f32x4 b0 = fz, b1 = fz;
            #pragma unroll
            for (int s_ = 0; s_ < 8; ++s_) {
                b0 = __builtin_amdgcn_mfma_f32_16x16x32_bf16(afrag[0][s_], bv[s_], b0, 0, 0, 0);
                b1 = __builtin_amdgcn_mfma_f32_16x16x32_bf16(afrag[1][s_], bv[s_], b1, 0, 0, 0);
            }
            const int cbase = (T0 + t) * 16;
            const float sec = se_reg[t];
            #pragma unroll
            for (int r = 0; r < 4; ++r) {
                float s0 = fmaf(-2.f, b0[r], sec);
                float s1 = fmaf(-2.f, b1[r], sec);
                if (s0 <= th[0][r]) {
                    int row = g * 4 + r;
                    unsigned int p = atomicAdd(&cnt[row], 1u);
                    if (p < (unsigned)CANDC) cand[row][p] = (unsigned int)(cbase + cc);
                }
                if (s1 <= th[1][r]) {
                    int row = 16 + g * 4 + r;
                    unsigned int p = atomicAdd(&cnt[row], 1u);
                    if (p < (unsigned)CANDC) cand[row][p] = (unsigned int)(cbase + cc);
                }
            }
        }
    }
    __syncthreads();

    // ---- PASS C: exact fp32 rescore of candidates (tie -> lower code) ----
    {
        const int r  = tid >> 3;
        const int sl = tid & 7;
        const unsigned int n = cnt[r];
        const bool ovf = (n > (unsigned)CANDC);
        const unsigned int total = ovf ? (unsigned)KCODES : n;
        const float sxr = sxl[r];
        const float4* xr  = (const float4*)x + (size_t)(n0 + r) * 64;
        const float4* cb4 = (const float4*)cb;
        for (unsigned int j = sl; j < total; j += 8) {
            unsigned int code = ovf ? j : cand[r][j];
            const float4* er = cb4 + (size_t)code * 64;
            float4 a4 = make_float4(0.f, 0.f, 0.f, 0.f);
            #pragma unroll 8
            for (int m2 = 0; m2 < 64; ++m2) {
                float4 xv = xr[m2];
                float4 ev = er[m2];
                FMA4(a4, xv, ev);
            }
            float dot  = (a4.x + a4.y) + (a4.z + a4.w);
            float tt   = __fadd_rn(sxr, se_arr[code]);
            float dist = __fsub_rn(tt, 2.0f * dot);
            unsigned long long pk =
                ((unsigned long long)__float_as_uint(dist) << 32) | (unsigned long long)code;
            atomicMin(&win[r], pk);
        }
    }
    __syncthreads();
    if (tid < RPB) {
        unsigned int code = (unsigned int)(win[tid] & 0xFFFFFFFFull);
        wcode[tid] = code;
        out_idx[n0 + tid] = (float)code;
    }
    __syncthreads();

    // ---- outputs (bit-exact straight-through) + fp64 loss partial ----
    double lacc = 0.0;
    {
        const float4* x4  = (const float4*)x;
        const float4* cb4 = (const float4*)cb;
        float4* q4 = (float4*)out_q;
        #pragma unroll
        for (int i = 0; i < 8; ++i) {
            int flat = tid + 256 * i;       // 0..2047 (32 rows x 64 float4)
            int row  = flat >> 6;
            int d4   = flat & 63;
            float4 xv = x4[(size_t)n0 * 64 + flat];
            float4 qv = cb4[(size_t)wcode[row] * 64 + d4];
            float dfx = __fsub_rn(qv.x, xv.x);
            float dfy = __fsub_rn(qv.y, xv.y);
            float dfz = __fsub_rn(qv.z, xv.z);
            float dfw = __fsub_rn(qv.w, xv.w);
            float4 o;
            o.x = __fadd_rn(xv.x, dfx);
            o.y = __fadd_rn(xv.y, dfy);
            o.z = __fadd_rn(xv.z, dfz);
            o.w = __fadd_rn(xv.w, dfw);
            lacc += (double)dfx * dfx + (double)dfy * dfy
                  + (double)dfz * dfz + (double)dfw * dfw;
            q4[(size_t)n0 * 64 + flat] = o;
        }
    }
    #pragma unroll
    for (int off = 32; off > 0; off >>= 1)
        lacc += __shfl_down(lacc, off, 64);
    if (lane == 0) lsum[w] = lacc;
    __syncthreads();
    if (tid == 0)
        atomicAdd(loss_acc, (lsum[0] + lsum[1]) + (lsum[2] + lsum[3]));
}

__global__ void finalize_loss(const double* __restrict__ acc,
                              float* __restrict__ out_loss) {
    if (threadIdx.x == 0 && blockIdx.x == 0)
        *out_loss = (float)(*acc / (double)(NROWS * DIM));
}

extern "C" void kernel_launch(void* const* d_in, const int* in_sizes, int n_in,
                              void* d_out, int out_size, void* d_ws, size_t ws_size,
                              hipStream_t stream) {
    const float* x  = (const float*)d_in[0];
    const float* cb = (const float*)d_in[1];
    float* out      = (float*)d_out;
    float* out_q    = out;                        // 8388608 elements
    float* out_idx  = out + (size_t)NROWS * DIM;  // 32768 elements (as float)
    float* out_loss = out_idx + NROWS;            // 1 element

    char* ws = (char*)d_ws;
    double* acc = (double*)ws;
    float* se   = (float*)(ws + WS_SE);
    float* sacb = (float*)(ws + WS_SACB);
    unsigned short* cbbf = (unsigned short*)(ws + WS_CBBF);

    init_ws<<<1, 1, 0, stream>>>(acc);
    rowsq_kernel<<<KCODES / 16, 256, 0, stream>>>(cb, se, sacb, KCODES);
    cvt_cb_kernel<<<128, 256, 0, stream>>>(cb, cbbf);
    vq_score<<<NROWS / RPB, 256, 0, stream>>>(x, cb, se, cbbf,
                                              out_q, out_idx, acc);
    finalize_loss<<<1, 1, 0, stream>>>(acc, out_loss);
}